// Round 12
// baseline (292.609 us; speedup 1.0000x reference)
//
#include <hip/hip_runtime.h>
#include <stdint.h>

#define ROUNDS 64
#define HIDDEN 256
#define BATCH  65536
#define NSUP   16   // super-rounds: 16 chains of 4 rounds each

typedef int   v4i  __attribute__((ext_vector_type(4)));
typedef int   v8i  __attribute__((ext_vector_type(8)));
typedef float v16f __attribute__((ext_vector_type(16)));
typedef unsigned long long u64;

// ============================================================================
// PARTIAL ALGEBRAIC COLLAPSE. Each round is affine over GF(2): s' = Whar s ^ n
// (Whar = (W!=0), -1 === 1 mod 2; remainder(int,2) == bit0). R8-R11 evidence:
// a compose costs ~10us no matter what (latency/barrier floor) and each launch
// boundary ~20us. So: collapse 64 rounds into 16 super-rounds of 4
// (M_g = W_{4g+3}..W_{4g}, c_g), giving a 3-compose critical path with all 16
// chains independent, then run the PROVEN R3 batch kernel for 16 rounds.
// Fusion: bitpack lives in the fold kernel; per-group tickets (16) make the
// last-arriving block of each 16-block group that group's fold block — it
// depends only on its own group's bitpack writes (fixes R11's global-dep trap).
// ============================================================================

// ws layout (bytes)
#define WB_OFF   0u         // W bits [64][256][4] u64 = 512 KB
#define NB_OFF   524288u    // n bits [64][4] u64      = 2 KB
#define WPK_OFF  526336u    // fp4 A-frags [g=16][mt=8][ks=4][lane=64][16B] = 512 KB
#define NF_OFF   1050624u   // noise floats [g=16][mt=8][lh=2][j=16] f32 = 16 KB
#define TK_OFF   1067008u   // tickets: 16 ints = 64 B

// sigma: nibble slot n (0..31) within a 32-k chunk holds logical k-offset
// rho(n). Applied identically to M-pack and state-pack so it cancels.
__host__ __device__ constexpr int rho(int n) {
  return 4 * (n >> 4) + (n & 3) + 8 * ((n >> 2) & 3);
}

// Per-C-slot bias (epilogue v_add_f32, IEEE-exact; round-1 FAILED note: bias
// must stay OUTSIDE the MFMA C-init; noise/c in {0,1} as C-init is proven).
__host__ __device__ constexpr float bias_q(int q) {
  return (q == 0) ? 6291456.0f   // 1.5*2^22 -> parity at bit 1
       : (q == 1) ? 393216.0f    // 1.5*2^18 -> bit 5
       : (q == 2) ? 24576.0f     // 1.5*2^14 -> bit 9
                  : 1536.0f;     // 1.5*2^10 -> bit 13
}

// ---- chain compose on one block's LDS state (R8-R11-verified algorithm,
// rolling 1-step register prefetch). (A,a) <- compose maps [base, base+count).
__device__ __forceinline__ void fold_stream(u64 (&A)[256][5],
                                            u64 (&tbl)[64][16][5],
                                            u64 (&avec)[4],
                                            const u64* __restrict__ inM,
                                            const u64* __restrict__ inV,
                                            int base, int count,
                                            int tid, int w, int i) {
  A[i][w] = inM[(size_t)base * 1024 + i * 4 + w];
  if (tid < 4) avec[tid] = inV[base * 4 + tid];
  u64 brP[4];
  u64 bwP;
  {  // prefetch step j=1's B row / vector word
    const u64* Bm = inM + (size_t)(base + 1) * 1024;
#pragma unroll
    for (int q = 0; q < 4; ++q) brP[q] = Bm[i * 4 + q];
    bwP = (tid < 256) ? inV[(size_t)(base + 1) * 4 + (i >> 6)] : 0ull;
  }
  __syncthreads();

  for (int j = 1; j < count; ++j) {
    const u64 br0 = brP[0], br1 = brP[1], br2 = brP[2], br3 = brP[3];
    const u64 bwc = bwP;
    if (j + 1 < count) {  // next step's loads hide under the table build
      const u64* Bm = inM + (size_t)(base + j + 1) * 1024;
#pragma unroll
      for (int q = 0; q < 4; ++q) brP[q] = Bm[i * 4 + q];
      bwP = (tid < 256) ? inV[(size_t)(base + j + 1) * 4 + (i >> 6)] : 0ull;
    }
    u64 av0 = avec[0], av1 = avec[1], av2 = avec[2], av3 = avec[3];

    // build 4-bit combination table over A's rows (contraction index k)
    {
      const int c = tid >> 4, m = tid & 15;  // 1024 entries, 1/thread
      u64 t0 = 0, t1 = 0, t2 = 0, t3 = 0;
#pragma unroll
      for (int jj = 0; jj < 4; ++jj)
        if (m & (1 << jj)) {
          t0 ^= A[4 * c + jj][0]; t1 ^= A[4 * c + jj][1];
          t2 ^= A[4 * c + jj][2]; t3 ^= A[4 * c + jj][3];
        }
      tbl[c][m][0] = t0; tbl[c][m][1] = t1; tbl[c][m][2] = t2; tbl[c][m][3] = t3;
    }
    __syncthreads();

    // R[i] = XOR_{k: B[i][k]=1} A[k], word w — 4-way ILP over the 64 gathers
    const u64 brr[4] = {br0, br1, br2, br3};  // constant-indexed under unroll
    u64 a0 = 0, a1 = 0, a2 = 0, a3 = 0;
#pragma unroll
    for (int c = 0; c < 64; c += 4) {
      unsigned n0 = (unsigned)(brr[(c + 0) >> 4] >> (((c + 0) & 15) * 4)) & 15u;
      unsigned n1 = (unsigned)(brr[(c + 1) >> 4] >> (((c + 1) & 15) * 4)) & 15u;
      unsigned n2 = (unsigned)(brr[(c + 2) >> 4] >> (((c + 2) & 15) * 4)) & 15u;
      unsigned n3 = (unsigned)(brr[(c + 3) >> 4] >> (((c + 3) & 15) * 4)) & 15u;
      a0 ^= tbl[c + 0][n0][w];
      a1 ^= tbl[c + 1][n1][w];
      a2 ^= tbl[c + 2][n2][w];
      a3 ^= tbl[c + 3][n3][w];
    }
    u64 acc = (a0 ^ a1) ^ (a2 ^ a3);

    // a' = B*a ^ b : bit i = parity(popcount(Brow_i & a)) ^ b_i (waves 0..3)
    u64 mask = 0;
    if (tid < 256) {
      int p = __popcll(br0 & av0) + __popcll(br1 & av1) +
              __popcll(br2 & av2) + __popcll(br3 & av3);
      int bit = ((int)((bwc >> (i & 63)) & 1ull)) ^ (p & 1);
      mask = __ballot(bit);
    }
    __syncthreads();  // tbl/avec reads done before overwrite
    A[i][w] = acc;
    if (tid < 256 && (i & 63) == 0) avec[i >> 6] = mask;
    __syncthreads();
  }
}

// ---- 1) foldpack: 256 blocks x 1024. Phase 1: block blk bitpacks the
// contiguous float chunk [blk*16384, +16384) of W (so group g = blk>>4 covers
// exactly rounds [4g, 4g+4)) plus its 64-float slice of group-g noise.
// Phase 2: per-group ticket; the 16th arrival of group g becomes fold block g:
// composes its 4 rounds (3 composes) and packs M_g -> fp4 frags, c_g -> nf.
__global__ __launch_bounds__(1024) void foldpack(const float* __restrict__ mat,
                                                 const float* __restrict__ noi,
                                                 u64* __restrict__ wb,
                                                 u64* __restrict__ nb,
                                                 uint32_t* __restrict__ wpk,
                                                 float* __restrict__ nf,
                                                 int* __restrict__ tickets) {
  __shared__ u64 A[256][5];       // padded (bank spread)
  __shared__ u64 tbl[64][16][5];
  __shared__ u64 avec[4];
  __shared__ int lastf;
  const int tid = threadIdx.x;
  const int blk = blockIdx.x;
  const int g = blk >> 4;   // chain/group 0..15
  const int l = blk & 15;   // block-in-group

  // phase 1a: W bits — 16384 floats, 16 per thread, coalesced
  {
    const size_t base = (size_t)blk * 16384;
#pragma unroll
    for (int it = 0; it < 16; ++it) {
      size_t idx = base + (size_t)it * 1024 + tid;
      u64 m = __ballot(mat[idx] != 0.f);
      if ((tid & 63) == 0) wb[idx >> 6] = m;
    }
  }
  // phase 1b: noise bits — this block's 64-float slice of group g's noise
  if (tid < 64) {
    unsigned idx = (unsigned)g * 1024u + (unsigned)l * 64u + tid;
    u64 m = __ballot(noi[idx] != 0.f);
    if (tid == 0) nb[idx >> 6] = m;
  }
  __threadfence();  // release Wb/nb (device scope)
  if (tid == 0) lastf = (atomicAdd(&tickets[g], 1) == 15) ? 1 : 0;
  __syncthreads();
  if (!lastf) return;  // 15 of 16 blocks exit; last arrival folds — it only
  __threadfence();     // needs ITS group's writes (all 15 others arrived)

  // phase 2: compose rounds [4g, 4g+4) -> (M_g, c_g) in LDS A/avec
  fold_stream(A, tbl, avec, wb, nb, 4 * g, 4, tid, tid >> 8, tid & 255);

  // phase 3: inline pack (R10/R11-verified): M_g bits -> fp4 A-fragments
#pragma unroll
  for (int it = 0; it < 2; ++it) {
    unsigned tg = (unsigned)it * 1024u + tid;  // row*8 + kwin, 2048 total
    unsigned kwin = tg & 7u, row = tg >> 3;
    uint32_t wd[4] = {0, 0, 0, 0};
#pragma unroll
    for (int n = 0; n < 32; ++n) {
      int k = (int)kwin * 32 + rho(n);
      uint32_t bit = (uint32_t)((A[row][k >> 6] >> (k & 63)) & 1ull);
      wd[n >> 3] |= (bit * 2u) << ((n & 7) * 4);  // fp4 e2m1: +1 -> 0b0010
    }
    unsigned mt = row >> 5, lhh = kwin & 1u, ks = kwin >> 1;
    unsigned lane = lhh * 32u + (row & 31u);
    *(uint4*)(wpk + ((((unsigned)g * 32u + mt * 4u + ks) * 64u + lane) << 2)) =
        make_uint4(wd[0], wd[1], wd[2], wd[3]);
  }
  if (tid < 256) {  // nf[g][mt][lh][j] = c_g[row(j,lh,mt)]
    unsigned j = tid & 15u, lhh = (tid >> 4) & 1u, mt = (unsigned)tid >> 5;
    unsigned row = mt * 32u + (j & 3u) + 8u * (j >> 2) + 4u * lhh;
    nf[(unsigned)g * 256u + tid] = (float)((avec[row >> 6] >> (row & 63u)) & 1ull);
  }
}

// ---- 2) hash16: the PROVEN R3 hash4 structure, 16 super-rounds.
// Per round: S <- parity(M_g S + c_g). fp4 MFMA 32x32x64, K=256 in 4 steps,
// c_g as MFMA C-init, bias-trick epilogue, double-buffered LDS state,
// round-ahead A/NZ prefetch. 512 thr, 128 el/block, wave wv = M-tile wv. ----
__global__ __launch_bounds__(512, 4) void hash16(const uint32_t* __restrict__ wpk,
                                                 const float* __restrict__ nf,
                                                 const float* __restrict__ sta,
                                                 float* __restrict__ out) {
  __shared__ uint8_t T[2][8][128][16];  // 32 KB
  const int t = threadIdx.x;
  const int wv = __builtin_amdgcn_readfirstlane(t >> 6);
  const int lane = t & 63;
  const int l31 = lane & 31;
  const int lh = lane >> 5;
  const int el0 = blockIdx.x * 128;

  // initial pack: f32 -> sigma-ordered fp4 nibbles into T[0]
#pragma unroll
  for (int i = 0; i < 16; ++i) {
    unsigned flat = (unsigned)i * 512u + t;
    unsigned el = flat >> 6, k4 = flat & 63u;
    float4 f = ((const float4*)(sta + (size_t)el0 * 256))[flat];
    uint32_t v = ((f.x != 0.f) ? 0x2u : 0u) | ((f.y != 0.f) ? 0x20u : 0u) |
                 ((f.z != 0.f) ? 0x200u : 0u) | ((f.w != 0.f) ? 0x2000u : 0u);
    unsigned KB = k4 >> 3, k4c = k4 & 7u;
    unsigned byteoff = (k4c & 1u) * 8u + 2u * (k4c >> 1);  // sigma^-1 of 4 rows
    *(uint16_t*)&T[0][KB][el][byteoff] = (uint16_t)v;
  }
  __syncthreads();

  // prefetch round-0 A fragments + c C-init
  v4i ap[4];
  {
    const uint32_t* wb = wpk + ((wv * 4) << 8);
#pragma unroll
    for (int ks = 0; ks < 4; ++ks) ap[ks] = *(const v4i*)(wb + ks * 256 + lane * 4);
  }
  v16f NZ = *(const v16f*)(nf + (wv * 2 + lh) * 16);

  for (int r = 0; r < NSUP; ++r) {
    const int rb = r & 1, nx = rb ^ 1;
    v16f acc[4];
    __builtin_amdgcn_s_setprio(1);
#pragma unroll
    for (int ks = 0; ks < 4; ++ks) {
      // fp4 fmt uses only regs 0..3 of the 8-reg operand: 4..7 stay undef.
      v8i A8 = __builtin_shufflevector(ap[ks], ap[ks], 0, 1, 2, 3, -1, -1, -1, -1);
      const int kb = 2 * ks + lh;
#pragma unroll
      for (int tn = 0; tn < 4; ++tn) {
        v4i b4 = *(const v4i*)&T[rb][kb][tn * 32 + l31][0];  // conflict-free b128
        v8i B8 = __builtin_shufflevector(b4, b4, 0, 1, 2, 3, -1, -1, -1, -1);
        acc[tn] = __builtin_amdgcn_mfma_scale_f32_32x32x64_f8f6f4(
            A8, B8, (ks == 0) ? NZ : acc[tn], 4, 4, 0, 127, 0, 127);
      }
    }
    __builtin_amdgcn_s_setprio(0);

    // prefetch next round's A + NZ (r=15 wraps to 0 -> no OOB, dead value)
    {
      const int rn = (r + 1) & (NSUP - 1);
      const uint32_t* wb = wpk + (((rn * 8 + wv) * 4) << 8);
#pragma unroll
      for (int ks = 0; ks < 4; ++ks) ap[ks] = *(const v4i*)(wb + ks * 256 + lane * 4);
      NZ = *(const v16f*)(nf + ((rn * 8 + wv) * 2 + lh) * 16);
    }

    // epilogue: per-slot bias (exact) puts slot j's parity bit at mantissa
    // bit 4*(j&3)+1 == its target nibble-bit; mask + or-chain.
#pragma unroll
    for (int tn = 0; tn < 4; ++tn) {
#define PB(j)                                                          \
  (__builtin_bit_cast(uint32_t, acc[tn][j] + bias_q((j) & 3)) &        \
   (2u << (4 * ((j) & 3))))
      uint32_t u0 = PB(0) | PB(1) | PB(2) | PB(3);
      uint32_t u1 = PB(4) | PB(5) | PB(6) | PB(7);
      uint32_t u2 = PB(8) | PB(9) | PB(10) | PB(11);
      uint32_t u3 = PB(12) | PB(13) | PB(14) | PB(15);
#undef PB
      *(uint2*)&T[nx][wv][tn * 32 + l31][lh * 8] =
          make_uint2(u0 | (u1 << 16), u2 | (u3 << 16));
    }

    __syncthreads();  // single barrier/round (double-buffered state)
  }

  // ---- final unpack: 16 rounds (even) -> buf 0 holds the output ----
#pragma unroll
  for (int i = 0; i < 16; ++i) {
    unsigned flat = (unsigned)i * 512u + t;
    unsigned el = flat >> 6, k4 = flat & 63u;
    unsigned KB = k4 >> 3, k4c = k4 & 7u;
    unsigned byteoff = (k4c & 1u) * 8u + 2u * (k4c >> 1);
    uint32_t v = *(const uint16_t*)&T[0][KB][el][byteoff];
    float4 o = make_float4((float)((v >> 1) & 1u), (float)((v >> 5) & 1u),
                           (float)((v >> 9) & 1u), (float)((v >> 13) & 1u));
    ((float4*)(out + (size_t)el0 * 256))[flat] = o;
  }
}

extern "C" void kernel_launch(void* const* d_in, const int* in_sizes, int n_in,
                              void* d_out, int out_size, void* d_ws, size_t ws_size,
                              hipStream_t stream) {
  const float* sta = (const float*)d_in[0];  // [B, HIDDEN]
  const float* mat = (const float*)d_in[1];  // [ROUNDS, HIDDEN, HIDDEN]
  const float* noi = (const float*)d_in[2];  // [ROUNDS, HIDDEN]
  uint8_t* wsb = (uint8_t*)d_ws;             // needs ~1.02 MB

  u64* Wb       = (u64*)(wsb + WB_OFF);
  u64* nb       = (u64*)(wsb + NB_OFF);
  uint32_t* wpk = (uint32_t*)(wsb + WPK_OFF);
  float* nf     = (float*)(wsb + NF_OFF);
  int* tickets  = (int*)(wsb + TK_OFF);

  hipMemsetAsync(tickets, 0, 16 * sizeof(int), stream);  // graph-safe, async
  foldpack<<<256, 1024, 0, stream>>>(mat, noi, Wb, nb, wpk, nf, tickets);
  hash16<<<512, 512, 0, stream>>>(wpk, nf, sta, (float*)d_out);
}

// Round 13
// 207.155 us; speedup vs baseline: 1.4125x; 1.4125x over previous
//
#include <hip/hip_runtime.h>
#include <stdint.h>

#define ROUNDS 64
#define HIDDEN 256
#define BATCH  65536
#define NSUP   16   // super-rounds: 16 chains of 4 rounds each

typedef int   v4i  __attribute__((ext_vector_type(4)));
typedef int   v8i  __attribute__((ext_vector_type(8)));
typedef float v16f __attribute__((ext_vector_type(16)));
typedef unsigned long long u64;

// ============================================================================
// PARTIAL ALGEBRAIC COLLAPSE (math+packing verified exact in R12). Each round
// is affine over GF(2): s' = Whar s ^ n. Collapse 64 rounds into 16
// super-rounds of 4: M_g = W_{4g+3}..W_{4g}, c_g folded constant; then the
// PROVEN R3 batch kernel runs 16 rounds.
// R10-R12 lesson (measured): ANY intra-kernel cross-block dependency costs
// ~100-150us on this stack (coop grid.sync 111us; ticket+threadfence 150us)
// while a launch boundary costs ~20us. So R13 uses 3 stream-ordered launches
// and ZERO intra-kernel cross-block sync: bitpack -> fold16 (16 independent
// blocks, block-local only) -> hash16.
// ============================================================================

// ws layout (bytes)
#define WB_OFF   0u         // W bits [64][256][4] u64 = 512 KB
#define NB_OFF   524288u    // n bits [64][4] u64      = 2 KB
#define WPK_OFF  526336u    // fp4 A-frags [g=16][mt=8][ks=4][lane=64][16B] = 512 KB
#define NF_OFF   1050624u   // noise floats [g=16][mt=8][lh=2][j=16] f32 = 16 KB

// sigma: nibble slot n (0..31) within a 32-k chunk holds logical k-offset
// rho(n). Applied identically to M-pack and state-pack so it cancels.
__host__ __device__ constexpr int rho(int n) {
  return 4 * (n >> 4) + (n & 3) + 8 * ((n >> 2) & 3);
}

// Per-C-slot bias (epilogue v_add_f32, IEEE-exact; round-1 FAILED note: bias
// must stay OUTSIDE the MFMA C-init; c in {0,1} as C-init is proven).
__host__ __device__ constexpr float bias_q(int q) {
  return (q == 0) ? 6291456.0f   // 1.5*2^22 -> parity at bit 1
       : (q == 1) ? 393216.0f    // 1.5*2^18 -> bit 5
       : (q == 2) ? 24576.0f     // 1.5*2^14 -> bit 9
                  : 1536.0f;     // 1.5*2^10 -> bit 13
}

// ---- 1) bitpack: W floats -> row-major bit matrix; noise -> bit vectors ----
__global__ __launch_bounds__(256) void bitpack(const float* __restrict__ mat,
                                               const float* __restrict__ noi,
                                               u64* __restrict__ wb,
                                               u64* __restrict__ nb) {
  unsigned blk = blockIdx.x;
  if (blk >= 16384u) {  // noise: 64*256 bits
    unsigned tg = (blk - 16384u) * 256u + threadIdx.x;  // < 16384
    u64 m = __ballot(noi[tg] != 0.f);
    if ((threadIdx.x & 63u) == 0u) nb[tg >> 6] = m;
    return;
  }
  unsigned tg = blk * 256u + threadIdx.x;  // element index into [64][256][256]
  u64 m = __ballot(mat[tg] != 0.f);
  if ((threadIdx.x & 63u) == 0u) wb[tg >> 6] = m;
}

// ---- chain compose on one block's LDS state (R8-R12-verified algorithm,
// rolling 1-step register prefetch). (A,a) <- compose maps [base, base+count).
__device__ __forceinline__ void fold_stream(u64 (&A)[256][5],
                                            u64 (&tbl)[64][16][5],
                                            u64 (&avec)[4],
                                            const u64* __restrict__ inM,
                                            const u64* __restrict__ inV,
                                            int base, int count,
                                            int tid, int w, int i) {
  A[i][w] = inM[(size_t)base * 1024 + i * 4 + w];
  if (tid < 4) avec[tid] = inV[base * 4 + tid];
  u64 brP[4];
  u64 bwP;
  {  // prefetch step j=1's B row / vector word
    const u64* Bm = inM + (size_t)(base + 1) * 1024;
#pragma unroll
    for (int q = 0; q < 4; ++q) brP[q] = Bm[i * 4 + q];
    bwP = (tid < 256) ? inV[(size_t)(base + 1) * 4 + (i >> 6)] : 0ull;
  }
  __syncthreads();

  for (int j = 1; j < count; ++j) {
    const u64 br0 = brP[0], br1 = brP[1], br2 = brP[2], br3 = brP[3];
    const u64 bwc = bwP;
    if (j + 1 < count) {  // next step's loads hide under the table build
      const u64* Bm = inM + (size_t)(base + j + 1) * 1024;
#pragma unroll
      for (int q = 0; q < 4; ++q) brP[q] = Bm[i * 4 + q];
      bwP = (tid < 256) ? inV[(size_t)(base + j + 1) * 4 + (i >> 6)] : 0ull;
    }
    u64 av0 = avec[0], av1 = avec[1], av2 = avec[2], av3 = avec[3];

    // build 4-bit combination table over A's rows (contraction index k)
    {
      const int c = tid >> 4, m = tid & 15;  // 1024 entries, 1/thread
      u64 t0 = 0, t1 = 0, t2 = 0, t3 = 0;
#pragma unroll
      for (int jj = 0; jj < 4; ++jj)
        if (m & (1 << jj)) {
          t0 ^= A[4 * c + jj][0]; t1 ^= A[4 * c + jj][1];
          t2 ^= A[4 * c + jj][2]; t3 ^= A[4 * c + jj][3];
        }
      tbl[c][m][0] = t0; tbl[c][m][1] = t1; tbl[c][m][2] = t2; tbl[c][m][3] = t3;
    }
    __syncthreads();

    // R[i] = XOR_{k: B[i][k]=1} A[k], word w — 4-way ILP over the 64 gathers
    const u64 brr[4] = {br0, br1, br2, br3};  // constant-indexed under unroll
    u64 a0 = 0, a1 = 0, a2 = 0, a3 = 0;
#pragma unroll
    for (int c = 0; c < 64; c += 4) {
      unsigned n0 = (unsigned)(brr[(c + 0) >> 4] >> (((c + 0) & 15) * 4)) & 15u;
      unsigned n1 = (unsigned)(brr[(c + 1) >> 4] >> (((c + 1) & 15) * 4)) & 15u;
      unsigned n2 = (unsigned)(brr[(c + 2) >> 4] >> (((c + 2) & 15) * 4)) & 15u;
      unsigned n3 = (unsigned)(brr[(c + 3) >> 4] >> (((c + 3) & 15) * 4)) & 15u;
      a0 ^= tbl[c + 0][n0][w];
      a1 ^= tbl[c + 1][n1][w];
      a2 ^= tbl[c + 2][n2][w];
      a3 ^= tbl[c + 3][n3][w];
    }
    u64 acc = (a0 ^ a1) ^ (a2 ^ a3);

    // a' = B*a ^ b : bit i = parity(popcount(Brow_i & a)) ^ b_i (waves 0..3)
    u64 mask = 0;
    if (tid < 256) {
      int p = __popcll(br0 & av0) + __popcll(br1 & av1) +
              __popcll(br2 & av2) + __popcll(br3 & av3);
      int bit = ((int)((bwc >> (i & 63)) & 1ull)) ^ (p & 1);
      mask = __ballot(bit);
    }
    __syncthreads();  // tbl/avec reads done before overwrite
    A[i][w] = acc;
    if (tid < 256 && (i & 63) == 0) avec[i >> 6] = mask;
    __syncthreads();
  }
}

// ---- 2) fold16: 16 INDEPENDENT blocks. Block g composes rounds [4g, 4g+4)
// (3 block-local composes; wb/nb written by the PREVIOUS launch — no fences,
// no tickets) and packs M_g -> fp4 A-fragments, c_g -> nf floats. ----
__global__ __launch_bounds__(1024) void fold16(const u64* __restrict__ wb,
                                               const u64* __restrict__ nb,
                                               uint32_t* __restrict__ wpk,
                                               float* __restrict__ nf) {
  __shared__ u64 A[256][5];       // padded (bank spread)
  __shared__ u64 tbl[64][16][5];
  __shared__ u64 avec[4];
  const int tid = threadIdx.x;
  const int g = blockIdx.x;  // chain/group 0..15

  fold_stream(A, tbl, avec, wb, nb, 4 * g, 4, tid, tid >> 8, tid & 255);

  // inline pack (R10-R12-verified): M_g bits -> fp4 A-fragments
#pragma unroll
  for (int it = 0; it < 2; ++it) {
    unsigned tg = (unsigned)it * 1024u + tid;  // row*8 + kwin, 2048 total
    unsigned kwin = tg & 7u, row = tg >> 3;
    uint32_t wd[4] = {0, 0, 0, 0};
#pragma unroll
    for (int n = 0; n < 32; ++n) {
      int k = (int)kwin * 32 + rho(n);
      uint32_t bit = (uint32_t)((A[row][k >> 6] >> (k & 63)) & 1ull);
      wd[n >> 3] |= (bit * 2u) << ((n & 7) * 4);  // fp4 e2m1: +1 -> 0b0010
    }
    unsigned mt = row >> 5, lhh = kwin & 1u, ks = kwin >> 1;
    unsigned lane = lhh * 32u + (row & 31u);
    *(uint4*)(wpk + ((((unsigned)g * 32u + mt * 4u + ks) * 64u + lane) << 2)) =
        make_uint4(wd[0], wd[1], wd[2], wd[3]);
  }
  if (tid < 256) {  // nf[g][mt][lh][j] = c_g[row(j,lh,mt)]
    unsigned j = tid & 15u, lhh = (tid >> 4) & 1u, mt = (unsigned)tid >> 5;
    unsigned row = mt * 32u + (j & 3u) + 8u * (j >> 2) + 4u * lhh;
    nf[(unsigned)g * 256u + tid] = (float)((avec[row >> 6] >> (row & 63u)) & 1ull);
  }
}

// ---- 3) hash16: the PROVEN R3 hash4 structure, 16 super-rounds (R12-verified).
// Per round: S <- parity(M_g S + c_g). fp4 MFMA 32x32x64, K=256 in 4 steps,
// c_g as MFMA C-init, bias-trick epilogue, double-buffered LDS state,
// round-ahead A/NZ prefetch. 512 thr, 128 el/block, wave wv = M-tile wv. ----
__global__ __launch_bounds__(512, 4) void hash16(const uint32_t* __restrict__ wpk,
                                                 const float* __restrict__ nf,
                                                 const float* __restrict__ sta,
                                                 float* __restrict__ out) {
  __shared__ uint8_t T[2][8][128][16];  // 32 KB
  const int t = threadIdx.x;
  const int wv = __builtin_amdgcn_readfirstlane(t >> 6);
  const int lane = t & 63;
  const int l31 = lane & 31;
  const int lh = lane >> 5;
  const int el0 = blockIdx.x * 128;

  // initial pack: f32 -> sigma-ordered fp4 nibbles into T[0]
#pragma unroll
  for (int i = 0; i < 16; ++i) {
    unsigned flat = (unsigned)i * 512u + t;
    unsigned el = flat >> 6, k4 = flat & 63u;
    float4 f = ((const float4*)(sta + (size_t)el0 * 256))[flat];
    uint32_t v = ((f.x != 0.f) ? 0x2u : 0u) | ((f.y != 0.f) ? 0x20u : 0u) |
                 ((f.z != 0.f) ? 0x200u : 0u) | ((f.w != 0.f) ? 0x2000u : 0u);
    unsigned KB = k4 >> 3, k4c = k4 & 7u;
    unsigned byteoff = (k4c & 1u) * 8u + 2u * (k4c >> 1);  // sigma^-1 of 4 rows
    *(uint16_t*)&T[0][KB][el][byteoff] = (uint16_t)v;
  }
  __syncthreads();

  // prefetch round-0 A fragments + c C-init
  v4i ap[4];
  {
    const uint32_t* wb = wpk + ((wv * 4) << 8);
#pragma unroll
    for (int ks = 0; ks < 4; ++ks) ap[ks] = *(const v4i*)(wb + ks * 256 + lane * 4);
  }
  v16f NZ = *(const v16f*)(nf + (wv * 2 + lh) * 16);

  for (int r = 0; r < NSUP; ++r) {
    const int rb = r & 1, nx = rb ^ 1;
    v16f acc[4];
    __builtin_amdgcn_s_setprio(1);
#pragma unroll
    for (int ks = 0; ks < 4; ++ks) {
      // fp4 fmt uses only regs 0..3 of the 8-reg operand: 4..7 stay undef.
      v8i A8 = __builtin_shufflevector(ap[ks], ap[ks], 0, 1, 2, 3, -1, -1, -1, -1);
      const int kb = 2 * ks + lh;
#pragma unroll
      for (int tn = 0; tn < 4; ++tn) {
        v4i b4 = *(const v4i*)&T[rb][kb][tn * 32 + l31][0];  // conflict-free b128
        v8i B8 = __builtin_shufflevector(b4, b4, 0, 1, 2, 3, -1, -1, -1, -1);
        acc[tn] = __builtin_amdgcn_mfma_scale_f32_32x32x64_f8f6f4(
            A8, B8, (ks == 0) ? NZ : acc[tn], 4, 4, 0, 127, 0, 127);
      }
    }
    __builtin_amdgcn_s_setprio(0);

    // prefetch next round's A + NZ (r=15 wraps to 0 -> no OOB, dead value)
    {
      const int rn = (r + 1) & (NSUP - 1);
      const uint32_t* wb = wpk + (((rn * 8 + wv) * 4) << 8);
#pragma unroll
      for (int ks = 0; ks < 4; ++ks) ap[ks] = *(const v4i*)(wb + ks * 256 + lane * 4);
      NZ = *(const v16f*)(nf + ((rn * 8 + wv) * 2 + lh) * 16);
    }

    // epilogue: per-slot bias (exact) puts slot j's parity bit at mantissa
    // bit 4*(j&3)+1 == its target nibble-bit; mask + or-chain.
#pragma unroll
    for (int tn = 0; tn < 4; ++tn) {
#define PB(j)                                                          \
  (__builtin_bit_cast(uint32_t, acc[tn][j] + bias_q((j) & 3)) &        \
   (2u << (4 * ((j) & 3))))
      uint32_t u0 = PB(0) | PB(1) | PB(2) | PB(3);
      uint32_t u1 = PB(4) | PB(5) | PB(6) | PB(7);
      uint32_t u2 = PB(8) | PB(9) | PB(10) | PB(11);
      uint32_t u3 = PB(12) | PB(13) | PB(14) | PB(15);
#undef PB
      *(uint2*)&T[nx][wv][tn * 32 + l31][lh * 8] =
          make_uint2(u0 | (u1 << 16), u2 | (u3 << 16));
    }

    __syncthreads();  // single barrier/round (double-buffered state)
  }

  // ---- final unpack: 16 rounds (even) -> buf 0 holds the output ----
#pragma unroll
  for (int i = 0; i < 16; ++i) {
    unsigned flat = (unsigned)i * 512u + t;
    unsigned el = flat >> 6, k4 = flat & 63u;
    unsigned KB = k4 >> 3, k4c = k4 & 7u;
    unsigned byteoff = (k4c & 1u) * 8u + 2u * (k4c >> 1);
    uint32_t v = *(const uint16_t*)&T[0][KB][el][byteoff];
    float4 o = make_float4((float)((v >> 1) & 1u), (float)((v >> 5) & 1u),
                           (float)((v >> 9) & 1u), (float)((v >> 13) & 1u));
    ((float4*)(out + (size_t)el0 * 256))[flat] = o;
  }
}

extern "C" void kernel_launch(void* const* d_in, const int* in_sizes, int n_in,
                              void* d_out, int out_size, void* d_ws, size_t ws_size,
                              hipStream_t stream) {
  const float* sta = (const float*)d_in[0];  // [B, HIDDEN]
  const float* mat = (const float*)d_in[1];  // [ROUNDS, HIDDEN, HIDDEN]
  const float* noi = (const float*)d_in[2];  // [ROUNDS, HIDDEN]
  uint8_t* wsb = (uint8_t*)d_ws;             // needs ~1.02 MB

  u64* Wb       = (u64*)(wsb + WB_OFF);
  u64* nb       = (u64*)(wsb + NB_OFF);
  uint32_t* wpk = (uint32_t*)(wsb + WPK_OFF);
  float* nf     = (float*)(wsb + NF_OFF);

  bitpack<<<16448, 256, 0, stream>>>(mat, noi, Wb, nb);
  fold16<<<16, 1024, 0, stream>>>(Wb, nb, wpk, nf);
  hash16<<<512, 512, 0, stream>>>(wpk, nf, sta, (float*)d_out);
}